// Round 2
// baseline (291.377 us; speedup 1.0000x reference)
//
#include <hip/hip_runtime.h>

// x: [8, 64, 256, 256] f32, d: [8, 3, 64, 7, 7] f32, out: [8, 3, 256, 256] f32
// circular padding 3, per-sample filters.
//
// Race-free by construction: no LDS, no barriers, no atomics. Each wave owns
// 2 output rows; 64 lanes x 4 px = W=256, circular column halo via modular
// lane shuffle (lane+-1 mod 64). Input planes double-buffered in registers.

constexpr int NB   = 8;
constexpr int CIN  = 64;
constexpr int HH   = 256;
constexpr int WW   = 256;
constexpr int COUT = 3;
constexpr int KK   = 7;

__global__ __launch_bounds__(256, 1)
void conv_shfl_f32(const float* __restrict__ x, const float* __restrict__ d,
                   float* __restrict__ out) {
    const int tid  = threadIdx.x;
    const int lane = tid & 63;
    const int wv   = tid >> 6;                       // wave 0..3
    const int b    = blockIdx.x >> 5;                // 32 blocks per image
    const int y0   = (blockIdx.x & 31) * 8 + wv * 2; // first of 2 output rows

    const int lleft  = (lane + 63) & 63;             // circular left neighbor
    const int lright = (lane + 1) & 63;              // circular right neighbor

    const float* xb = x + (size_t)b * CIN * HH * WW;
    const float* db = d + (size_t)b * COUT * CIN * KK * KK;

    float acc[COUT][2][4] = {};
    float4 bufA[8], bufB[8];

    // load 8 rows (y0-3 .. y0+4, circular) of plane ci, one float4 per lane/row
    auto load8 = [&](float4 (&buf)[8], int ci) {
        const float* p = xb + (size_t)ci * HH * WW + lane * 4;
        #pragma unroll
        for (int r = 0; r < 8; ++r) {
            const int row = (y0 + r - 3) & (HH - 1);
            buf[r] = *reinterpret_cast<const float4*>(p + row * WW);
        }
    };

    auto compute = [&](const float4 (&buf)[8], int ci) {
        const float* wp = db + ci * (KK * KK);
        #pragma unroll
        for (int r = 0; r < 8; ++r) {
            const float4 v = buf[r];
            float xw[10];                // x cols lane*4-3 .. lane*4+6
            xw[3] = v.x; xw[4] = v.y; xw[5] = v.z; xw[6] = v.w;
            xw[0] = __shfl(v.y, lleft);
            xw[1] = __shfl(v.z, lleft);
            xw[2] = __shfl(v.w, lleft);
            xw[7] = __shfl(v.x, lright);
            xw[8] = __shfl(v.y, lright);
            xw[9] = __shfl(v.z, lright);
            #pragma unroll
            for (int co = 0; co < COUT; ++co) {
                #pragma unroll
                for (int t = 0; t < 2; ++t) {
                    const int ky = r - t;            // out row y0+t uses ky = r-t
                    if (ky < 0 || ky >= KK) continue;
                    #pragma unroll
                    for (int kx = 0; kx < KK; ++kx) {
                        const float w = wp[co * (CIN * KK * KK) + ky * KK + kx];
                        #pragma unroll
                        for (int p = 0; p < 4; ++p)
                            acc[co][t][p] += w * xw[p + kx];
                    }
                }
            }
        }
    };

    load8(bufA, 0);
    for (int ci = 0; ci < CIN; ci += 2) {
        load8(bufB, ci + 1);            // issue next-plane loads early
        compute(bufA, ci);
        if (ci + 2 < CIN) load8(bufA, ci + 2);
        compute(bufB, ci + 1);
    }

    #pragma unroll
    for (int co = 0; co < COUT; ++co) {
        #pragma unroll
        for (int t = 0; t < 2; ++t) {
            const float4 v = make_float4(acc[co][t][0], acc[co][t][1],
                                         acc[co][t][2], acc[co][t][3]);
            *reinterpret_cast<float4*>(
                out + (((size_t)(b * COUT + co) * HH + (y0 + t)) * WW + lane * 4)) = v;
        }
    }
}

extern "C" void kernel_launch(void* const* d_in, const int* in_sizes, int n_in,
                              void* d_out, int out_size, void* d_ws, size_t ws_size,
                              hipStream_t stream) {
    const float* x = (const float*)d_in[0];
    const float* d = (const float*)d_in[1];
    float* out    = (float*)d_out;
    dim3 grid(NB * (HH / 8));   // 256 blocks, one per CU
    conv_shfl_f32<<<grid, 256, 0, stream>>>(x, d, out);
}

// Round 3
// 60.614 us; speedup vs baseline: 4.8071x; 4.8071x over previous
//
#include <hip/hip_runtime.h>
#include <stdint.h>

// out[b][co][y][x0] = sum_{ci,ky,kx} x[b][ci][(y+ky-3)%256][(x0+kx-3)%256] * d[b][co][ci][ky][kx]
//
// Per (b,y) GEMM: tmp[x'][n=co*8+kx] = sum_{ci,ky} Xpad[ci][y+ky][x'] * w[co][ci][ky][kx]
// (periodic in x' with period 256), epilogue: out = sum_kx tmp[(x0+kx)&255][co*8+kx].
// MFMA 32x32x16 bf16; A from LDS x-major/ci-inner (b128 frags), B in LDS fragment-order.

constexpr int NB = 8, CIN = 64, HH = 256, WW = 256, CO = 3, KK = 7;
constexpr int R = 4;            // output rows per block
constexpr int XROWS = 10;       // staged rows r=0..9 (input rows y0-3..y0+6); r==10 (ky=7 pad) wraps to 0
constexpr int CI_CHUNK = 8;

typedef short bf16x8 __attribute__((ext_vector_type(8)));
typedef float f32x16 __attribute__((ext_vector_type(16)));

__device__ inline uint16_t f2bf(float f) {
    uint32_t u = __builtin_bit_cast(uint32_t, f);
    u += 0x7fffu + ((u >> 16) & 1u);     // RNE
    return (uint16_t)(u >> 16);
}

// LDS: X region 10*256*8 u16 = 40960 B | B region 16*64*8 u16 = 16384 B. tmp f32[256][33] aliases X.
__global__ __launch_bounds__(512, 1)
void conv_mfma_bf16(const float* __restrict__ x, const float* __restrict__ d,
                    float* __restrict__ out) {
    __shared__ char smem[57344];
    uint16_t* Xl = (uint16_t*)smem;                 // [r][xp][ci8]
    uint16_t* Bl = (uint16_t*)(smem + 40960);       // [frag(16)][lane(64)][8]
    float*    tmp = (float*)smem;                   // [256][33]

    const int tid = threadIdx.x;
    const int lane = tid & 63, wv = tid >> 6;
    const int y_t = wv >> 1, xh = wv & 1;           // wave: row y0+y_t, x-half xh
    const int l31 = lane & 31, lh = lane >> 5;

    const int b  = blockIdx.x >> 6;                 // 64 row-blocks per image
    const int y0 = (blockIdx.x & 63) * R;

    const float* xb = x + (size_t)b * CIN * HH * WW;
    const float* db = d + (size_t)b * CO * CIN * KK * KK;

    f32x16 acc[4];
    #pragma unroll
    for (int m = 0; m < 4; ++m)
        #pragma unroll
        for (int i = 0; i < 16; ++i) acc[m][i] = 0.f;

    for (int c = 0; c < CIN / CI_CHUNK; ++c) {
        __syncthreads();
        // ---- stage X chunk: 10 rows x 256 xp x 8 ci (bf16), rotation applied ----
        {
            const int ci0 = c * CI_CHUNK;
            #pragma unroll
            for (int k = 0; k < 5; ++k) {
                const int item = tid + k * 512;     // 2560 items
                const int r = item >> 8, xp = item & 255;
                const int row = (y0 + r - 3) & (HH - 1);
                const int col = (xp - 3) & (WW - 1);
                const float* p = xb + ((size_t)ci0 * HH + row) * WW + col;
                uint32_t w0, w1, w2, w3;
                {
                    float v0 = p[0*HH*WW], v1 = p[1*HH*WW], v2 = p[2*HH*WW], v3 = p[3*HH*WW];
                    float v4 = p[4*HH*WW], v5 = p[5*HH*WW], v6 = p[6*HH*WW], v7 = p[7*HH*WW];
                    w0 = (uint32_t)f2bf(v0) | ((uint32_t)f2bf(v1) << 16);
                    w1 = (uint32_t)f2bf(v2) | ((uint32_t)f2bf(v3) << 16);
                    w2 = (uint32_t)f2bf(v4) | ((uint32_t)f2bf(v5) << 16);
                    w3 = (uint32_t)f2bf(v6) | ((uint32_t)f2bf(v7) << 16);
                }
                uint4 pk = make_uint4(w0, w1, w2, w3);
                *reinterpret_cast<uint4*>(&Xl[(size_t)(r * 256 + xp) * 8]) = pk;
            }
        }
        // ---- stage B half (at c==0: ci 0..31, c==4: ci 32..63), fragment order ----
        if ((c & 3) == 0) {
            const int half = c >> 2;
            #pragma unroll
            for (int q = 0; q < 2; ++q) {
                const int s = tid * 2 + q;          // 1024 slots
                const int fi = s >> 6, ln = s & 63;
                const int cc4 = fi >> 2, ks = fi & 3;
                const int h = ln >> 5, n = ln & 31;
                const int ky = ks * 2 + h;
                const int co = n >> 3, kx = n & 7;
                const int cib = (half * 4 + cc4) * 8;
                uint16_t vals[8];
                #pragma unroll
                for (int j = 0; j < 8; ++j) {
                    float v = 0.f;
                    if (co < 3 && kx < 7 && ky < 7)
                        v = db[((size_t)co * CIN + (cib + j)) * (KK * KK) + ky * KK + kx];
                    vals[j] = f2bf(v);
                }
                uint32_t w0 = (uint32_t)vals[0] | ((uint32_t)vals[1] << 16);
                uint32_t w1 = (uint32_t)vals[2] | ((uint32_t)vals[3] << 16);
                uint32_t w2 = (uint32_t)vals[4] | ((uint32_t)vals[5] << 16);
                uint32_t w3 = (uint32_t)vals[6] | ((uint32_t)vals[7] << 16);
                *reinterpret_cast<uint4*>(&Bl[(size_t)(fi * 64 + ln) * 8]) =
                    make_uint4(w0, w1, w2, w3);
            }
        }
        __syncthreads();
        // ---- compute: 4 k-steps (ky pairs) x 4 m-frags ----
        #pragma unroll
        for (int ks = 0; ks < 4; ++ks) {
            const int ky = ks * 2 + lh;             // per-lane ky
            int r = y_t + ky;                       // <= 10
            if (r >= XROWS) r = 0;                  // r==10 only when ky==7 (zero weight)
            const int arow = r * (256 * 8);
            const int fi = (c & 3) * 4 + ks;
            const bf16x8 bfrag = *reinterpret_cast<const bf16x8*>(&Bl[(size_t)(fi * 64 + lane) * 8]);
            #pragma unroll
            for (int m = 0; m < 4; ++m) {
                const int xp = xh * 128 + m * 32 + l31;
                const bf16x8 afrag = *reinterpret_cast<const bf16x8*>(&Xl[arow + xp * 8]);
                acc[m] = __builtin_amdgcn_mfma_f32_32x32x16_bf16(afrag, bfrag, acc[m], 0, 0, 0);
            }
        }
    }

    // ---- epilogue: per output row, dump tmp[x'][n] then reduce over kx ----
    for (int p = 0; p < R; ++p) {
        __syncthreads();
        if (y_t == p) {
            #pragma unroll
            for (int m = 0; m < 4; ++m)
                #pragma unroll
                for (int reg = 0; reg < 16; ++reg) {
                    const int rowloc = (reg & 3) + 8 * (reg >> 2) + 4 * lh;
                    const int xp = xh * 128 + m * 32 + rowloc;
                    tmp[xp * 33 + l31] = acc[m][reg];
                }
        }
        __syncthreads();
        const int y = y0 + p;
        {
            const int x0 = tid & 255;
            const int co = tid >> 8;                // 0 or 1
            float s = 0.f;
            #pragma unroll
            for (int kx = 0; kx < 7; ++kx)
                s += tmp[((x0 + kx) & 255) * 33 + co * 8 + kx];
            out[(((size_t)b * CO + co) * HH + y) * WW + x0] = s;
            if (tid < 256) {
                float s2 = 0.f;
                #pragma unroll
                for (int kx = 0; kx < 7; ++kx)
                    s2 += tmp[((x0 + kx) & 255) * 33 + 16 + kx];
                out[(((size_t)b * CO + 2) * HH + y) * WW + x0] = s2;
            }
        }
    }
}

extern "C" void kernel_launch(void* const* d_in, const int* in_sizes, int n_in,
                              void* d_out, int out_size, void* d_ws, size_t ws_size,
                              hipStream_t stream) {
    const float* x = (const float*)d_in[0];
    const float* d = (const float*)d_in[1];
    float* out    = (float*)d_out;
    conv_mfma_bf16<<<dim3(NB * (HH / R)), 512, 0, stream>>>(x, d, out);
}

// Round 4
// 50.089 us; speedup vs baseline: 5.8172x; 1.2101x over previous
//
#include <hip/hip_runtime.h>
#include <hip/hip_bf16.h>
#include <stdint.h>

// out[b][co][y][x0] = sum_{ci,ky,kx} x[b][ci][(y+ky-3)%256][(x0+kx-3)%256] * d[b][co][ci][ky][kx]
//
// Per (b, y-tile) GEMM: tmp[u][n=co*8+kx] = sum_{ci,ky} X[ci][(y+ky-3)%256][u] * w[co][ci][ky][kx]
// (u = REAL column, periodic 256); epilogue: out[x0] = sum_kx tmp[(x0+kx-3)&255][co*8+kx].
// MFMA 32x32x16 bf16, fragment scheme verified in round 3.

constexpr int NB = 8, CIN = 64, HH = 256, WW = 256, CO = 3, KK = 7;
constexpr int R = 8;             // output rows per block
constexpr int XROWS = 14;        // staged rows r=0..13 (input y0-3 .. y0+10)
constexpr int CI_CHUNK = 8;
constexpr int NCH = CIN / CI_CHUNK;

typedef short bf16x8 __attribute__((ext_vector_type(8)));
typedef float f32x16 __attribute__((ext_vector_type(16)));

__device__ inline uint16_t f2bf(float f) {
    union { __hip_bfloat16 h; uint16_t u; } cv;
    cv.h = __float2bfloat16(f);          // HW RNE convert
    return cv.u;
}

// LDS: Xl u16[14*256*8]=57344B | Bl u16[16*64*8]=16384B  (total 73728B)
// epilogue tmp f32[256][33]=33792B aliases Xl.
__global__ __launch_bounds__(1024, 4)
void conv_mfma_v2(const float* __restrict__ x, const float* __restrict__ d,
                  float* __restrict__ out) {
    __shared__ char smem[XROWS * 256 * 8 * 2 + 16 * 64 * 8 * 2];
    uint16_t* Xl  = (uint16_t*)smem;                       // [r][xs(swizzled xp)][ci8]
    uint16_t* Bl  = (uint16_t*)(smem + XROWS * 256 * 8 * 2); // [frag16][lane64][8]
    float*    tmp = (float*)smem;                          // [256][33]

    const int tid  = threadIdx.x;
    const int lane = tid & 63, wv = tid >> 6;              // 16 waves
    const int y_t  = wv >> 1, xh = wv & 1;                 // wave: row y0+y_t, x-half
    const int l31  = lane & 31, lh = lane >> 5;

    const int b  = blockIdx.x >> 5;                        // 32 row-blocks per image
    const int y0 = (blockIdx.x & 31) * R;

    const float* xb = x + (size_t)b * CIN * HH * WW;
    const float* db = d + (size_t)b * CO * CIN * KK * KK;

    f32x16 acc[4];
    #pragma unroll
    for (int m = 0; m < 4; ++m)
        #pragma unroll
        for (int i = 0; i < 16; ++i) acc[m][i] = 0.f;

    for (int c = 0; c < NCH; ++c) {
        __syncthreads();
        // ---- stage X chunk: 14 rows x 256 real cols x 8 ci, aligned float4 loads ----
        if (tid < XROWS * 64) {                            // 896 active threads
            const int r = tid >> 6, q = tid & 63;          // q = col quad
            const int row = (y0 + r - 3) & (HH - 1);
            const float* p = xb + ((size_t)(c * CI_CHUNK) * HH + row) * WW + q * 4;
            float4 v[8];
            #pragma unroll
            for (int j = 0; j < 8; ++j)
                v[j] = *reinterpret_cast<const float4*>(p + (size_t)j * HH * WW);
            #pragma unroll
            for (int t = 0; t < 4; ++t) {
                const float e0 = ((const float*)&v[0])[t], e1 = ((const float*)&v[1])[t];
                const float e2 = ((const float*)&v[2])[t], e3 = ((const float*)&v[3])[t];
                const float e4 = ((const float*)&v[4])[t], e5 = ((const float*)&v[5])[t];
                const float e6 = ((const float*)&v[6])[t], e7 = ((const float*)&v[7])[t];
                uint4 pk;
                pk.x = (uint32_t)f2bf(e0) | ((uint32_t)f2bf(e1) << 16);
                pk.y = (uint32_t)f2bf(e2) | ((uint32_t)f2bf(e3) << 16);
                pk.z = (uint32_t)f2bf(e4) | ((uint32_t)f2bf(e5) << 16);
                pk.w = (uint32_t)f2bf(e6) | ((uint32_t)f2bf(e7) << 16);
                const int xp = q * 4 + t;
                const int xs = xp ^ ((xp >> 2) & 3);       // bank swizzle (involution)
                *reinterpret_cast<uint4*>(&Xl[(size_t)(r * 256 + xs) * 8]) = pk;
            }
        }
        // ---- stage B half (c==0: ci 0..31, c==4: ci 32..63), fragment order ----
        if ((c & 3) == 0) {
            const int half = c >> 2;
            const int s = tid;                             // 1024 slots
            const int fi = s >> 6, ln = s & 63;
            const int cc4 = fi >> 2, ks = fi & 3;
            const int h = ln >> 5, n = ln & 31;
            const int ky = ks * 2 + h;
            const int co = n >> 3, kx = n & 7;
            const int cib = (half * 4 + cc4) * 8;
            uint16_t vals[8];
            #pragma unroll
            for (int j = 0; j < 8; ++j) {
                float v = 0.f;
                if (co < 3 && kx < 7 && ky < 7)
                    v = db[((size_t)co * CIN + (cib + j)) * (KK * KK) + ky * KK + kx];
                vals[j] = f2bf(v);
            }
            uint4 pk;
            pk.x = (uint32_t)vals[0] | ((uint32_t)vals[1] << 16);
            pk.y = (uint32_t)vals[2] | ((uint32_t)vals[3] << 16);
            pk.z = (uint32_t)vals[4] | ((uint32_t)vals[5] << 16);
            pk.w = (uint32_t)vals[6] | ((uint32_t)vals[7] << 16);
            *reinterpret_cast<uint4*>(&Bl[(size_t)(fi * 64 + ln) * 8]) = pk;
        }
        __syncthreads();
        // ---- compute: 4 k-steps (ky pairs) x 4 m-frags ----
        #pragma unroll
        for (int ks = 0; ks < 4; ++ks) {
            const int ky = ks * 2 + lh;                    // per-lane ky
            int r = y_t + ky;                              // <= 14
            if (r >= XROWS) r = 0;                         // only y_t=7,ky=7 (zero weight)
            const int fi = (c & 3) * 4 + ks;
            const bf16x8 bfrag = *reinterpret_cast<const bf16x8*>(&Bl[(size_t)(fi * 64 + lane) * 8]);
            #pragma unroll
            for (int m = 0; m < 4; ++m) {
                const int xr = xh * 128 + m * 32 + l31;    // real column (no shift!)
                const int xs = xr ^ ((xr >> 2) & 3);
                const bf16x8 afrag = *reinterpret_cast<const bf16x8*>(&Xl[(size_t)(r * 256 + xs) * 8]);
                acc[m] = __builtin_amdgcn_mfma_f32_32x32x16_bf16(afrag, bfrag, acc[m], 0, 0, 0);
            }
        }
    }

    // ---- epilogue: per output row, dump tmp[u][n] then kx-reduce ----
    for (int p = 0; p < R; ++p) {
        __syncthreads();
        if (y_t == p) {
            #pragma unroll
            for (int m = 0; m < 4; ++m)
                #pragma unroll
                for (int reg = 0; reg < 16; ++reg) {
                    const int rowloc = (reg & 3) + 8 * (reg >> 2) + 4 * lh;
                    const int u = xh * 128 + m * 32 + rowloc;
                    tmp[u * 33 + l31] = acc[m][reg];
                }
        }
        __syncthreads();
        if (tid < CO * 256) {
            const int co = tid >> 8, x0 = tid & 255;
            float s = 0.f;
            #pragma unroll
            for (int kx = 0; kx < 7; ++kx)
                s += tmp[((x0 + kx - 3) & 255) * 33 + co * 8 + kx];
            out[(((size_t)b * CO + co) * HH + (y0 + p)) * WW + x0] = s;
        }
    }
}

extern "C" void kernel_launch(void* const* d_in, const int* in_sizes, int n_in,
                              void* d_out, int out_size, void* d_ws, size_t ws_size,
                              hipStream_t stream) {
    const float* x = (const float*)d_in[0];
    const float* d = (const float*)d_in[1];
    float* out    = (float*)d_out;
    conv_mfma_v2<<<dim3(NB * (HH / R)), 1024, 0, stream>>>(x, d, out);
}

// Round 5
// 39.195 us; speedup vs baseline: 7.4340x; 1.2779x over previous
//
#include <hip/hip_runtime.h>
#include <hip/hip_bf16.h>
#include <stdint.h>

// out[b][co][y][x0] = sum_{ci,ky,kx} x[b][ci][(y+ky-3)%256][(x0+kx-3)%256] * d[b][co][ci][ky][kx]
// Per (b,y-tile) GEMM: tmp[u][n=co*8+kx] = sum_{ci,ky} X[ci][(y+ky-3)%256][u] * w[co][ci][ky][kx]
// epilogue: out[x0] = sum_kx tmp[(x0+kx-3)&255][co*8+kx].  MFMA 32x32x16 bf16 (scheme verified r3/r4).
// v3: XCD-swizzled grid (halo re-reads hit per-XCD L2), double-buffered X chunks
// (stage c+1 overlaps compute c, one barrier per chunk), B fully staged in prologue,
// 4-round epilogue.

constexpr int NB = 8, CIN = 64, HH = 256, WW = 256, CO = 3, KK = 7;
constexpr int R = 8;             // output rows per block
constexpr int XROWS = 14;        // staged rows r=0..13 (input y0-3 .. y0+10)
constexpr int CI_CHUNK = 8;
constexpr int NCH = CIN / CI_CHUNK;
constexpr int XBUF = XROWS * 256 * 8;    // u16 elements per X buffer (28672)

typedef short bf16x8 __attribute__((ext_vector_type(8)));
typedef float f32x16 __attribute__((ext_vector_type(16)));

__device__ inline uint16_t f2bf(float f) {
    union { __hip_bfloat16 h; uint16_t u; } cv;
    cv.h = __float2bfloat16(f);          // HW RNE convert
    return cv.u;
}

// LDS: Xl[2][14][256][8] bf16 = 114688 B | Bl[32][64][8] bf16 = 32768 B  (147456 total)
// epilogue tmp f32[2][256][33] = 67584 B aliases Xl.
__global__ __launch_bounds__(1024, 4)
void conv_mfma_v3(const float* __restrict__ x, const float* __restrict__ d,
                  float* __restrict__ out) {
    __shared__ char smem[2 * XBUF * 2 + 32 * 64 * 8 * 2];
    uint16_t* Xl  = (uint16_t*)smem;
    uint16_t* Bl  = (uint16_t*)(smem + 2 * XBUF * 2);
    float*    tmp = (float*)smem;                      // [2][256][33]

    const int tid  = threadIdx.x;
    const int lane = tid & 63, wv = tid >> 6;          // 16 waves
    const int y_t  = wv >> 1, xh = wv & 1;
    const int l31  = lane & 31, lh = lane >> 5;

    // XCD swizzle: XCD (blk%8) owns image b=blk%8; its 32 blocks cover adjacent
    // y-tiles -> halo rows shared via that XCD's L2.
    const int blk = blockIdx.x;
    const int b   = blk & 7;
    const int y0  = (blk >> 3) * R;

    const float* xb = x + (size_t)b * CIN * HH * WW;
    const float* db = d + (size_t)b * CO * CIN * KK * KK;

    f32x16 acc[4];
    #pragma unroll
    for (int m = 0; m < 4; ++m)
        #pragma unroll
        for (int i = 0; i < 16; ++i) acc[m][i] = 0.f;

    // ---- stage chunk c of X into buffer `buf` (aligned float4 loads, bf16 pack) ----
    auto stageX = [&](int c, int buf) {
        if (tid < XROWS * 64) {                        // 896 active threads
            const int r = tid >> 6, q = tid & 63;
            const int row = (y0 + r - 3) & (HH - 1);
            const float* p = xb + ((size_t)(c * CI_CHUNK) * HH + row) * WW + q * 4;
            float4 v[8];
            #pragma unroll
            for (int j = 0; j < 8; ++j)
                v[j] = *reinterpret_cast<const float4*>(p + (size_t)j * HH * WW);
            uint16_t* dst = Xl + (size_t)buf * XBUF + (size_t)r * 256 * 8;
            #pragma unroll
            for (int t = 0; t < 4; ++t) {
                uint4 pk;
                pk.x = (uint32_t)f2bf(((const float*)&v[0])[t]) | ((uint32_t)f2bf(((const float*)&v[1])[t]) << 16);
                pk.y = (uint32_t)f2bf(((const float*)&v[2])[t]) | ((uint32_t)f2bf(((const float*)&v[3])[t]) << 16);
                pk.z = (uint32_t)f2bf(((const float*)&v[4])[t]) | ((uint32_t)f2bf(((const float*)&v[5])[t]) << 16);
                pk.w = (uint32_t)f2bf(((const float*)&v[6])[t]) | ((uint32_t)f2bf(((const float*)&v[7])[t]) << 16);
                const int xp = q * 4 + t;
                const int xs = xp ^ ((xp >> 2) & 3);   // bank swizzle (involution)
                *reinterpret_cast<uint4*>(dst + (size_t)xs * 8) = pk;
            }
        }
    };

    // ---- compute chunk c from buffer `buf` ----
    auto compute = [&](int c, int buf) {
        const uint16_t* Xb = Xl + (size_t)buf * XBUF;
        #pragma unroll
        for (int ks = 0; ks < 4; ++ks) {
            const int ky = ks * 2 + lh;
            int r = y_t + ky;                          // <= 14
            if (r >= XROWS) r = 0;                     // only y_t=7,ky=7 (zero weight)
            const int fi = c * 4 + ks;
            const bf16x8 bfrag = *reinterpret_cast<const bf16x8*>(&Bl[(size_t)(fi * 64 + lane) * 8]);
            #pragma unroll
            for (int m = 0; m < 4; ++m) {
                const int xr = xh * 128 + m * 32 + l31;
                const int xs = xr ^ ((xr >> 2) & 3);
                const bf16x8 afrag = *reinterpret_cast<const bf16x8*>(&Xb[((size_t)r * 256 + xs) * 8]);
                acc[m] = __builtin_amdgcn_mfma_f32_32x32x16_bf16(afrag, bfrag, acc[m], 0, 0, 0);
            }
        }
    };

    // ---- prologue: X chunk 0 + ALL of B (32 frags, fragment order) ----
    stageX(0, 0);
    #pragma unroll
    for (int q2 = 0; q2 < 2; ++q2) {
        const int s = tid + q2 * 1024;                 // 2048 slots
        const int fi = s >> 6, ln = s & 63;
        const int cc8 = fi >> 2, ks = fi & 3;
        const int h = ln >> 5, n = ln & 31;
        const int ky = ks * 2 + h, co = n >> 3, kx = n & 7;
        uint16_t vals[8];
        #pragma unroll
        for (int j = 0; j < 8; ++j) {
            float v = 0.f;
            if (co < CO && kx < KK && ky < KK)
                v = db[((size_t)co * CIN + cc8 * 8 + j) * (KK * KK) + ky * KK + kx];
            vals[j] = f2bf(v);
        }
        uint4 pk;
        pk.x = (uint32_t)vals[0] | ((uint32_t)vals[1] << 16);
        pk.y = (uint32_t)vals[2] | ((uint32_t)vals[3] << 16);
        pk.z = (uint32_t)vals[4] | ((uint32_t)vals[5] << 16);
        pk.w = (uint32_t)vals[6] | ((uint32_t)vals[7] << 16);
        *reinterpret_cast<uint4*>(&Bl[(size_t)(fi * 64 + ln) * 8]) = pk;
    }

    // ---- main loop: one barrier per chunk; stage(c+1) overlaps compute(c) ----
    for (int c = 0; c < NCH; ++c) {
        __syncthreads();                               // buf[c&1] writes visible
        if (c + 1 < NCH) stageX(c + 1, (c + 1) & 1);   // writes opposite buffer
        compute(c, c & 1);
    }

    // ---- epilogue: 4 rounds x 2 rows; tmp[2][256][33] aliases Xl ----
    for (int p = 0; p < 4; ++p) {
        __syncthreads();
        if ((y_t >> 1) == p) {
            const int rr = y_t & 1;
            #pragma unroll
            for (int m = 0; m < 4; ++m)
                #pragma unroll
                for (int reg = 0; reg < 16; ++reg) {
                    const int rowloc = (reg & 3) + 8 * (reg >> 2) + 4 * lh;
                    const int u = xh * 128 + m * 32 + rowloc;
                    tmp[((size_t)rr * 256 + u) * 33 + l31] = acc[m][reg];
                }
        }
        __syncthreads();
        #pragma unroll
        for (int it0 = 0; it0 < 2; ++it0) {
            const int it = tid + it0 * 1024;
            if (it < 2 * CO * 256) {                   // 1536 items
                const int rr  = it >= CO * 256;
                const int rem = it - rr * CO * 256;
                const int co  = rem >> 8, x0 = rem & 255;
                float s = 0.f;
                #pragma unroll
                for (int kx = 0; kx < 7; ++kx)
                    s += tmp[((size_t)rr * 256 + ((x0 + kx - 3) & 255)) * 33 + co * 8 + kx];
                out[(((size_t)b * CO + co) * HH + (y0 + p * 2 + rr)) * WW + x0] = s;
            }
        }
    }
}

extern "C" void kernel_launch(void* const* d_in, const int* in_sizes, int n_in,
                              void* d_out, int out_size, void* d_ws, size_t ws_size,
                              hipStream_t stream) {
    const float* x = (const float*)d_in[0];
    const float* d = (const float*)d_in[1];
    float* out    = (float*)d_out;
    conv_mfma_v3<<<dim3(NB * (HH / R)), 1024, 0, stream>>>(x, d, out);
}